// Round 2
// baseline (472.559 us; speedup 1.0000x reference)
//
#include <hip/hip_runtime.h>
#include <hip/hip_bf16.h>

#define T_SEQ 2048
#define DMODEL 4096
#define NH 32
#define NKV 8
#define HD 128
#define RVIRT 128
#define TKV (RVIRT + T_SEQ)   // 2176

typedef __attribute__((ext_vector_type(8))) short s16x8;
typedef __attribute__((ext_vector_type(4))) short s16x4;
typedef __attribute__((ext_vector_type(4))) float f32x4;
typedef __attribute__((ext_vector_type(4))) float float4v;

static __device__ __forceinline__ short f2bf(float f) {
  union { __hip_bfloat16 h; short s; } u; u.h = __float2bfloat16(f); return u.s;
}

static __device__ __forceinline__ void gload16(const void* g, void* l) {
  __builtin_amdgcn_global_load_lds(
      (const __attribute__((address_space(1))) void*)g,
      (__attribute__((address_space(3))) void*)l, 16, 0, 0);
}

// ---------------------------------------------------------------------------
// fp32 -> bf16 convert (X). Each thread converts 8 elements.
// ---------------------------------------------------------------------------
__global__ __launch_bounds__(256) void convert_x(const float* __restrict__ src,
                                                 short* __restrict__ dst)
{
  int i = (blockIdx.x * 256 + threadIdx.x) * 8;
  float4v a = *(const float4v*)(src + i);
  float4v b = *(const float4v*)(src + i + 4);
  s16x8 o;
#pragma unroll
  for (int j = 0; j < 4; ++j) { o[j] = f2bf(a[j]); o[4 + j] = f2bf(b[j]); }
  *(s16x8*)(dst + i) = o;
}

// ---------------------------------------------------------------------------
// Transpose + convert: src [K][N] fp32 -> dst [N][K] bf16. 64x64 tiles.
// ---------------------------------------------------------------------------
__global__ __launch_bounds__(256) void transpose_convert(const float* __restrict__ src,
    short* __restrict__ dst, int K, int N)
{
  __shared__ float tile[64][65];
  const int k0 = blockIdx.y * 64, n0 = blockIdx.x * 64;
  const int tid = threadIdx.x;
  const int rr = tid >> 4, c4 = (tid & 15) * 4;
#pragma unroll
  for (int it = 0; it < 4; ++it) {
    int row = it * 16 + rr;
    float4v v = *(const float4v*)(src + (size_t)(k0 + row) * N + n0 + c4);
    tile[row][c4] = v[0]; tile[row][c4 + 1] = v[1];
    tile[row][c4 + 2] = v[2]; tile[row][c4 + 3] = v[3];
  }
  __syncthreads();
  const int n = tid >> 3, seg = tid & 7;
#pragma unroll
  for (int it = 0; it < 2; ++it) {
    int nn = it * 32 + n;
    s16x8 o;
#pragma unroll
    for (int j = 0; j < 8; ++j) o[j] = f2bf(tile[seg * 8 + j][nn]);
    *(s16x8*)(dst + (size_t)(n0 + nn) * K + k0 + seg * 8) = o;
  }
}

// ---------------------------------------------------------------------------
// gemm256 (8-phase schedule): C[M][N] = A[M][K] (bf16) x Bt[N][K] (bf16, B^T).
//  - BK=64 per tile; 2-slot LDS double buffer.
//    SLOT = A(256x64x2B = 32 KB) + 2 k-steps of B (NF*64 x 32 x 2B each).
//    NF=4: SLOT = 64 KB, total 128 KB.  NF=2: SLOT = 48 KB, total 96 KB.
//  - 4 phases per K-tile, phase = (M-half mh, K-step ks), order
//    (0,0),(1,0),(1,1),(0,1). Per phase: 4-8 ds_read_b128, issue 1-2 stage
//    units, barrier, lgkmcnt(0), setprio(1), 4*NF MFMA, setprio(0), barrier.
//  - Stage units (consumption-ordered, 2-slot ring):
//      ph0: Aq(0,1)(t+1), B(1)(t+1)   [slots last read ph3/ph2 of t-1]
//      ph1: Aq(0,0)(t+2)              [slot last read ph0 of t]
//      ph2: Aq(1,0)(t+2), B(0)(t+2)   [slots last read ph1/ph0 of t]
//      ph3: Aq(1,1)(t+2)              [slot last read ph2 of t]
//  - One counted vmcnt per K-tile at end of ph3: vmcnt(5) NF=4 / vmcnt(4)
//    NF=2 leaves exactly ph1-3's loads in flight and guarantees every unit of
//    tile t+1 (youngest issued at ph0 of t, ~3 phases of MFMA to cover HBM).
// ---------------------------------------------------------------------------
template<int NF, int EPI>
__global__ __launch_bounds__(512, 2) void gemm256(const short* __restrict__ Ab,
    const short* __restrict__ Btb, float* __restrict__ C0,
    float* __restrict__ Ck, short* __restrict__ Cv, int M, int N, int K)
{
  constexpr int A_BYTES = 32768;          // 256 rows x 64 k x 2B
  constexpr int B_KS    = NF * 4096;      // (NF*64) rows x 32 k x 2B (one k-step)
  constexpr int SLOT    = A_BYTES + 2 * B_KS;
  __shared__ __align__(16) char lds[2 * SLOT];
  const int tid = threadIdx.x, lane = tid & 63, w = tid >> 6;
  const int lo = lane & 15, g = lane >> 4;
  const int wm = w >> 2, wn = w & 3;
  const int wl = w & 3, wh = w >> 2;
  const int m0 = blockIdx.y * 256, n0 = blockIdx.x * (NF * 64);
  const int NT = K >> 6;

  // staging sources (per-lane addresses; row set matches LDS chunk layout)
  const short* As0 = Ab + (size_t)(m0 + (0 * 4 + wl + wh * 8) * 16 + lo) * K + g * 8; // mh=0 chunks
  const short* As1 = Ab + (size_t)(m0 + (1 * 4 + wl + wh * 8) * 16 + lo) * K + g * 8; // mh=1 chunks
  const short* Bs0 = Btb + (size_t)(n0 + (NF == 4 ? w * 2     : w) * 16 + lo) * K + g * 8;
  const short* Bs1 = Btb + (size_t)(n0 + (NF == 4 ? w * 2 + 1 : w) * 16 + lo) * K + g * 8;

  // stage one A quarter-unit (mh, ks) of tile y: 1 gload16 per wave
  auto SAq = [&](int mh, int ks, int y) {
    char* dst = lds + (y & 1) * SLOT + ks * 16384 + (mh * 4 + wl + wh * 8) * 1024;
    gload16((mh ? As1 : As0) + y * 64 + ks * 32, dst);
  };
  // stage B k-step unit (ks) of tile y: 2 gload16 (NF=4) / 1 (NF=2) per wave
  auto SB = [&](int ks, int y) {
    char* base = lds + (y & 1) * SLOT + A_BYTES + ks * B_KS;
    if constexpr (NF == 4) {
      gload16(Bs0 + y * 64 + ks * 32, base + (w * 2) * 1024);
      gload16(Bs1 + y * 64 + ks * 32, base + (w * 2 + 1) * 1024);
    } else {
      gload16(Bs0 + y * 64 + ks * 32, base + w * 1024);
    }
  };

  f32x4 acc[8][NF];
#pragma unroll
  for (int i = 0; i < 8; ++i)
#pragma unroll
    for (int j = 0; j < NF; ++j) acc[i][j] = (f32x4){0.f, 0.f, 0.f, 0.f};

  // prologue: tile 0 complete + tile 1's "early" units (steady-state ph1-3)
  SAq(0, 0, 0); SB(0, 0); SAq(1, 0, 0); SAq(1, 1, 0); SB(1, 0); SAq(0, 1, 0);
  SAq(0, 0, 1); SAq(1, 0, 1); SB(0, 1); SAq(1, 1, 1);
  if constexpr (NF == 4) asm volatile("s_waitcnt vmcnt(5)" ::: "memory");
  else                   asm volatile("s_waitcnt vmcnt(4)" ::: "memory");
  __builtin_amdgcn_s_barrier();

#define DS_A(MH, KS) \
  { const char* pa_ = ab + (KS) * 16384 + (wm * 8 + (MH) * 4) * 1024 + g * 256 + lo * 16; \
    a4[0] = *(const s16x8*)(pa_); \
    a4[1] = *(const s16x8*)(pa_ + 1024); \
    a4[2] = *(const s16x8*)(pa_ + 2048); \
    a4[3] = *(const s16x8*)(pa_ + 3072); }
#define DS_B(KS) \
  { const char* pb_ = bb + (KS) * B_KS + (wn * NF) * 1024 + g * 256 + lo * 16; \
    _Pragma("unroll") \
    for (int j = 0; j < NF; ++j) bq[j] = *(const s16x8*)(pb_ + j * 1024); }
#define SYNC_IN() \
  __builtin_amdgcn_s_barrier(); \
  asm volatile("s_waitcnt lgkmcnt(0)" ::: "memory"); \
  __builtin_amdgcn_sched_barrier(0);
#define MFMA_Q(MH) \
  __builtin_amdgcn_s_setprio(1); \
  _Pragma("unroll") \
  for (int i = 0; i < 4; ++i) \
    _Pragma("unroll") \
    for (int j = 0; j < NF; ++j) \
      acc[(MH) * 4 + i][j] = __builtin_amdgcn_mfma_f32_16x16x32_bf16(a4[i], bq[j], acc[(MH) * 4 + i][j], 0, 0, 0); \
  __builtin_amdgcn_s_setprio(0);

  s16x8 bq[NF];
  for (int t = 0; t < NT; ++t) {
    const char* ab = lds + (t & 1) * SLOT;
    const char* bb = ab + A_BYTES;
    s16x8 a4[4];
    // ---- phase 0: (mh=0, ks=0)
    DS_A(0, 0); DS_B(0);
    if (t + 1 < NT) { SAq(0, 1, t + 1); SB(1, t + 1); }
    SYNC_IN(); MFMA_Q(0);
    __builtin_amdgcn_s_barrier();
    // ---- phase 1: (mh=1, ks=0), reuse bq
    DS_A(1, 0);
    if (t + 2 < NT) SAq(0, 0, t + 2);
    SYNC_IN(); MFMA_Q(1);
    __builtin_amdgcn_s_barrier();
    // ---- phase 2: (mh=1, ks=1)
    DS_A(1, 1); DS_B(1);
    if (t + 2 < NT) { SAq(1, 0, t + 2); SB(0, t + 2); }
    SYNC_IN(); MFMA_Q(1);
    __builtin_amdgcn_s_barrier();
    // ---- phase 3: (mh=0, ks=1), reuse bq; boundary vmcnt (counted, not 0)
    DS_A(0, 1);
    if (t + 2 < NT) SAq(1, 1, t + 2);
    SYNC_IN(); MFMA_Q(0);
    if (t + 2 < NT) {
      if constexpr (NF == 4) asm volatile("s_waitcnt vmcnt(5)" ::: "memory");
      else                   asm volatile("s_waitcnt vmcnt(4)" ::: "memory");
    } else {
      asm volatile("s_waitcnt vmcnt(0)" ::: "memory");
    }
    __builtin_amdgcn_s_barrier();
  }
#undef DS_A
#undef DS_B
#undef SYNC_IN
#undef MFMA_Q

#pragma unroll
  for (int i = 0; i < 8; ++i)
#pragma unroll
    for (int j = 0; j < NF; ++j)
#pragma unroll
      for (int r = 0; r < 4; ++r) {
        int row = m0 + wm * 128 + i * 16 + g * 4 + r;
        int col = n0 + wn * (NF * 16) + j * 16 + lo;
        float val = acc[i][j][r];
        if (EPI == 0) {
          C0[(size_t)row * N + col] = val;
        } else {
          if (col < 4096) C0[(size_t)row * 4096 + col] = val;
          else if (col < 5120) Ck[(size_t)row * 1024 + (col - 4096)] = val;
          else {
            int vcol = col - 5120;
            Cv[(size_t)((vcol >> 7) * HD + (vcol & 127)) * TKV + RVIRT + row] = f2bf(val);
          }
        }
      }
}

// ---------------------------------------------------------------------------
// RMSNorm + RoPE. One wave per (t, head). qs folds 1/sqrt(HD) into Q.
// ---------------------------------------------------------------------------
__global__ __launch_bounds__(256) void rope_kernel(const float* __restrict__ proj,
    const float* __restrict__ nw, const float* __restrict__ cosT,
    const float* __restrict__ sinT, short* __restrict__ out,
    int nh_shift, int rows_total, int row0, float qs)
{
  int wid = blockIdx.x * 4 + (threadIdx.x >> 6);
  int lane = threadIdx.x & 63;
  int nh = 1 << nh_shift;
  int t = wid >> nh_shift;
  int hh = wid & (nh - 1);
  const float* src = proj + (size_t)t * (nh * HD) + hh * HD;
  float x1 = src[lane];
  float x2 = src[lane + 64];
  float ss = x1 * x1 + x2 * x2;
#pragma unroll
  for (int off = 32; off > 0; off >>= 1) ss += __shfl_xor(ss, off, 64);
  float rms = rsqrtf(ss * (1.0f / 128.0f) + 1e-6f);
  float n1 = x1 * rms * nw[lane];
  float n2 = x2 * rms * nw[lane + 64];
  float c1 = cosT[t * HD + lane], c2 = cosT[t * HD + lane + 64];
  float s1 = sinT[t * HD + lane], s2 = sinT[t * HD + lane + 64];
  short* dst = out + ((size_t)hh * rows_total + row0 + t) * HD;
  dst[lane]      = f2bf((n1 * c1 - n2 * s1) * qs);
  dst[lane + 64] = f2bf((n2 * c2 + n1 * s2) * qs);
}

// ---------------------------------------------------------------------------
// Virtual KV injection.
// ---------------------------------------------------------------------------
__global__ __launch_bounds__(256) void inject_kernel(const float* __restrict__ vk,
    const float* __restrict__ vv, const float* __restrict__ logit,
    short* __restrict__ Kr, short* __restrict__ Vt)
{
  int idx = blockIdx.x * 256 + threadIdx.x;   // < 8*128*128
  float alpha = 0.5f / (1.0f + __expf(-logit[0]));
  int kv = idx >> 14, rem = idx & 16383, r = rem >> 7, d = rem & 127;
  Kr[((size_t)kv * TKV + r) * HD + d] = f2bf(vk[idx] * alpha);
  Vt[((size_t)kv * HD + d) * TKV + r] = f2bf(vv[idx] * alpha);
}

// ---------------------------------------------------------------------------
// Flash attention v4 = r5's staged structure + r6's cheap softmax.
//  - K/V tiles staged in LDS (reg-staged, async split: issue loads for tile
//    t+1 before computing tile t; ds_write after the barrier). 2 barriers/tile.
//  - Swapped QK^T: S^T = mfma(K_frag, Q_frag); lane owns q-column (q = lo);
//    m,l per-lane scalars; max/sum = 16 local ops + 2 shfl_xor.
//  - Defer-max (THR=8): O-rescale only when tile max grows > 8.
//  - P packed 4xbf16 ds_write_b64 into per-wave LDS in PV A-operand layout.
//  - Mask only the diagonal tile; Q pre-scaled by 1/sqrt(HD).
//  - q-tile pairing (bx, 31-bx) for causal load balance.
// ---------------------------------------------------------------------------
template<bool MASKED>
static __device__ __forceinline__ void attn_tile(
    const s16x8* qf, float& m, float& l, f32x4* o,
    const char* Ksb, const char* Vsb, char* Psw,
    int kvt, int qr, int lo, int g)
{
  // S^T: sfr[cj][r] = S[k = kvt*64 + cj*16 + g*4 + r][q = lo]
  f32x4 sfr[4];
#pragma unroll
  for (int cj = 0; cj < 4; ++cj) {
    f32x4 z = {};
    const int kr = cj * 16 + lo;
#pragma unroll
    for (int kk = 0; kk < 4; ++kk) {
      s16x8 kf = *(const s16x8*)(Ksb + ((kr * 256 + kk * 64 + g * 16) ^ ((kr & 7) << 4)));
      z = __builtin_amdgcn_mfma_f32_16x16x32_bf16(kf, qf[kk], z, 0, 0, 0);
    }
    sfr[cj] = z;
  }
  float mx = -3.0e38f;
#pragma unroll
  for (int cj = 0; cj < 4; ++cj)
#pragma unroll
    for (int r = 0; r < 4; ++r) {
      float s = sfr[cj][r];
      if (MASKED) {
        int k = kvt * 64 + cj * 16 + g * 4 + r;
        bool ok = (k < RVIRT) || (k - RVIRT <= qr);
        s = ok ? s : -3.0e38f;
        sfr[cj][r] = s;
      }
      mx = fmaxf(mx, s);
    }
  mx = fmaxf(mx, __shfl_xor(mx, 16, 64));
  mx = fmaxf(mx, __shfl_xor(mx, 32, 64));
  if (__any(mx > m + 8.0f)) {           // defer-max
    float mnew = fmaxf(m, mx);
    float fs = __expf(m - mnew);
    m = mnew;
    l *= fs;
#pragma unroll
    for (int r = 0; r < 4; ++r) {
      float fsq = __shfl(fs, g * 4 + r, 64);
#pragma unroll
      for (int dj = 0; dj < 8; ++dj) o[dj][r] *= fsq;
    }
  }
  float rowsum = 0.f;
#pragma unroll
  for (int cj = 0; cj < 4; ++cj) {
    s16x4 pk;
#pragma unroll
    for (int r = 0; r < 4; ++r) {
      float pv = __expf(sfr[cj][r] - m);   // masked lanes: exp(-inf) = 0
      rowsum += pv;
      pk[r] = f2bf(pv);
    }
    *(s16x4*)(Psw + ((lo * 128 + cj * 32 + g * 8) ^ ((lo & 7) << 4))) = pk;
  }
  rowsum += __shfl_xor(rowsum, 16, 64);
  rowsum += __shfl_xor(rowsum, 32, 64);
  l += rowsum;
  // PV: pf (A-layout) from per-wave LDS; vf from Vs LDS
  s16x8 pf[2];
#pragma unroll
  for (int k2 = 0; k2 < 2; ++k2)
    pf[k2] = *(const s16x8*)(Psw + ((lo * 128 + k2 * 64 + g * 16) ^ ((lo & 7) << 4)));
#pragma unroll
  for (int dj = 0; dj < 8; ++dj) {
    const int d = dj * 16 + lo;
    const int vswz = ((d ^ (d >> 3)) & 7) << 4;
#pragma unroll
    for (int k2 = 0; k2 < 2; ++k2) {
      s16x8 vf = *(const s16x8*)(Vsb + ((d * 128 + k2 * 64 + g * 16) ^ vswz));
      o[dj] = __builtin_amdgcn_mfma_f32_16x16x32_bf16(pf[k2], vf, o[dj], 0, 0, 0);
    }
  }
}

__global__ __launch_bounds__(256) void attn_kernel(const short* __restrict__ Qr,
    const short* __restrict__ Kr, const short* __restrict__ Vt,
    short* __restrict__ out)
{
  __shared__ short Ks[64 * 128];                // (r*256 + c*16) ^ ((r&7)<<4)
  __shared__ short Vs[128 * 64];                // (d*128 + c8*16) ^ (((d^(d>>3))&7)<<4)
  __shared__ __align__(16) char Ps[4 * 4096];   // per wave: 2KB A-set + 2KB B-set
  const int tid = threadIdx.x, lane = tid & 63, w = tid >> 6;
  const int h = blockIdx.y, kvh = h >> 2, bx = blockIdx.x;
  const int lo = lane & 15, g = lane >> 4;
  const int q0A = bx * 64, q0B = (31 - bx) * 64;
  char* PsA = Ps + w * 4096;
  char* PsB = PsA + 2048;
  const short* Kb = Kr + (size_t)kvh * TKV * HD;
  const short* Vb = Vt + (size_t)kvh * HD * TKV;

  s16x8 qfA[4], qfB[4];
#pragma unroll
  for (int kk = 0; kk < 4; ++kk) {
    qfA[kk] = *(const s16x8*)(Qr + ((size_t)h * T_SEQ + q0A + w * 16 + lo) * HD + kk * 32 + g * 8);
    qfB[kk] = *(const s16x8*)(Qr + ((size_t)h * T_SEQ + q0B + w * 16 + lo) * HD + kk * 32 + g * 8);
  }

  float mA = -3.0e38f, lA = 0.f, mB = -3.0e38f, lB = 0.f;
  f32x4 oA[8] = {}, oB[8] = {};
  const int ntA = bx + 3, ntB = 34 - bx;
  const int qrA = q0A + w * 16 + lo, qrB = q0B + w * 16 + lo;

  s16x8 kst[4], vst[4];
  auto ISSUE = [&](int kvt) {
#pragma unroll
    for (int p = 0; p < 4; ++p) {
      int ci = p * 256 + tid;
      kst[p] = *(const s16x8*)(Kb + (size_t)(kvt * 64 + (ci >> 4)) * HD + (ci & 15) * 8);
      vst[p] = *(const s16x8*)(Vb + (size_t)(ci >> 3) * TKV + kvt * 64 + (ci & 7) * 8);
    }
  };
  auto WRITE = [&]() {
#pragma unroll
    for (int p = 0; p < 4; ++p) {
      int ci = p * 256 + tid;
      int r = ci >> 4, c = ci & 15;
      *(s16x8*)((char*)Ks + ((r * 256 + c * 16) ^ ((r & 7) << 4))) = kst[p];
      int d = ci >> 3, c8 = ci & 7;
      *(s16x8*)((char*)Vs + ((d * 128 + c8 * 16) ^ (((d ^ (d >> 3)) & 7) << 4))) = vst[p];
    }
  };

  ISSUE(0);
  WRITE();
  __syncthreads();

  for (int kvt = 0; kvt < ntB; ++kvt) {
    if (kvt + 1 < ntB) ISSUE(kvt + 1);      // loads fly during compute
    if (kvt < ntA) {
      if (kvt == ntA - 1) attn_tile<true >(qfA, mA, lA, oA, (const char*)Ks, (const char*)Vs, PsA, kvt, qrA, lo, g);
      else                attn_tile<false>(qfA, mA, lA, oA, (const char*)Ks, (const char*)Vs, PsA, kvt, qrA, lo, g);
    }
    if (kvt == ntB - 1)   attn_tile<true >(qfB, mB, lB, oB, (const char*)Ks, (const char*)Vs, PsB, kvt, qrB, lo, g);
    else                  attn_tile<false>(qfB, mB, lB, oB, (const char*)Ks, (const char*)Vs, PsB, kvt, qrB, lo, g);
    __syncthreads();                         // all waves done reading tile kvt
    if (kvt + 1 < ntB) WRITE();              // waits vmcnt via reg dependence
    __syncthreads();                         // writes visible
  }
  // epilogue: o row q = g*4 + r; l lives on lane with lo == q (any g)
#pragma unroll
  for (int r = 0; r < 4; ++r) {
    float lqA = __shfl(lA, g * 4 + r, 64);
    float lqB = __shfl(lB, g * 4 + r, 64);
    float iA = 1.f / lqA, iB = 1.f / lqB;
#pragma unroll
    for (int dj = 0; dj < 8; ++dj) {
      int col = h * HD + dj * 16 + lo;
      int rowA = q0A + w * 16 + g * 4 + r;
      int rowB = q0B + w * 16 + g * 4 + r;
      out[(size_t)rowA * (NH * HD) + col] = f2bf(oA[dj][r] * iA);
      out[(size_t)rowB * (NH * HD) + col] = f2bf(oB[dj][r] * iB);
    }
  }
}

// ---------------------------------------------------------------------------
extern "C" void kernel_launch(void* const* d_in, const int* in_sizes, int n_in,
                              void* d_out, int out_size, void* d_ws, size_t ws_size,
                              hipStream_t stream)
{
  const float* hidden = (const float*)d_in[0];
  // d_in[1] = attention_mask: structurally known (causal + R visible), unused.
  const float* cosT = (const float*)d_in[2];
  const float* sinT = (const float*)d_in[3];
  const float* vk   = (const float*)d_in[4];
  const float* vv   = (const float*)d_in[5];
  const float* Wq   = (const float*)d_in[6];
  const float* Wk   = (const float*)d_in[7];
  const float* Wv   = (const float*)d_in[8];
  const float* Wo   = (const float*)d_in[9];
  const float* qnw  = (const float*)d_in[10];
  const float* knw  = (const float*)d_in[11];
  const float* alog = (const float*)d_in[12];

  char* ws = (char*)d_ws;
  float* q_projf = (float*)ws;                         // 33,554,432 B
  float* k_projf = (float*)(ws + 33554432);            //  8,388,608 B
  short* Vt      = (short*)(ws + 41943040);            //  4,456,448 B
  short* Qr      = (short*)(ws + 46399488);            // 16,777,216 B
  short* Kr      = (short*)(ws + 63176704);            //  4,456,448 B
  short* Xb      = (short*)(ws + 67633152);            // 16,777,216 B
  short* Wall    = (short*)(ws + 84410368);            // 50,331,648 B  (Wq|Wk|Wv)^T
  short* Wot     = Wall;                               // reused after QKV gemm
  short* attn_out = (short*)ws;                        // reuses q_projf (bf16)
  float* outp = (float*)d_out;

  const float qscale = 0.08838834764831845f;           // 128^-0.5

  dim3 blk(256);
  convert_x<<<dim3(T_SEQ * DMODEL / 8 / 256), blk, 0, stream>>>(hidden, Xb);
  transpose_convert<<<dim3(64, 64), blk, 0, stream>>>(Wq, Wall, DMODEL, 4096);
  transpose_convert<<<dim3(16, 64), blk, 0, stream>>>(Wk, Wall + (size_t)4096 * DMODEL, DMODEL, 1024);
  transpose_convert<<<dim3(16, 64), blk, 0, stream>>>(Wv, Wall + (size_t)5120 * DMODEL, DMODEL, 1024);
  gemm256<4, 3><<<dim3(24, 8), dim3(512), 0, stream>>>(Xb, Wall, q_projf, k_projf, Vt, T_SEQ, 6144, DMODEL);
  rope_kernel<<<dim3(T_SEQ * NH / 4),  blk, 0, stream>>>(q_projf, qnw, cosT, sinT, Qr, 5, T_SEQ, 0, qscale);
  rope_kernel<<<dim3(T_SEQ * NKV / 4), blk, 0, stream>>>(k_projf, knw, cosT, sinT, Kr, 3, TKV, RVIRT, 1.0f);
  inject_kernel<<<dim3(NKV * RVIRT * HD / 256), blk, 0, stream>>>(vk, vv, alog, Kr, Vt);
  attn_kernel<<<dim3(16, NH), blk, 0, stream>>>(Qr, Kr, Vt, attn_out);
  transpose_convert<<<dim3(64, 64), blk, 0, stream>>>(Wo, Wot, 4096, 4096);
  gemm256<2, 0><<<dim3(32, 8), dim3(512), 0, stream>>>(attn_out, Wot, outp, nullptr, nullptr, T_SEQ, 4096, 4096);
}